// Round 2
// baseline (4219.566 us; speedup 1.0000x reference)
//
#include <hip/hip_runtime.h>
#include <cmath>

#define B_  16
#define SEQ 2048   // S_CTX == S_Q
#define DIM 1024   // D_CTX == D_Q

// ---------------------------------------------------------------------------
// f32 tiled GEMM, 64x64 tile, BK=16, 256 threads, 4x4 micro-tile per thread.
// LDS inner stride 68 floats (= 272B, 16B-aligned rows, bank-shift of 4).
// ---------------------------------------------------------------------------

// cw[r, e] = sum_k context[r, k] * W[k, e]    (r = b*SEQ + s, M=32768, N=1024, K=1024)
__global__ __launch_bounds__(256) void kernel_cw(const float* __restrict__ A,
                                                 const float* __restrict__ Wm,
                                                 float* __restrict__ C) {
  __shared__ float As[16][68];   // As[k][m]
  __shared__ float Bs[16][68];   // Bs[k][n]
  const int tid = threadIdx.x;
  const int tx = tid & 15, ty = tid >> 4;
  const int m0 = blockIdx.y * 64, n0 = blockIdx.x * 64;

  const int lr = tid >> 2;         // 0..63  (A row within tile)
  const int lk = (tid & 3) * 4;    // 0,4,8,12
  const int br = tid >> 4;         // 0..15  (W row within k-slab)
  const int bn = (tid & 15) * 4;   // 0..60

  float4 av = *(const float4*)&A[(size_t)(m0 + lr) * DIM + lk];
  float4 bv = *(const float4*)&Wm[(size_t)br * DIM + n0 + bn];

  float acc[4][4] = {};
  for (int k0 = 0; k0 < DIM; k0 += 16) {
    As[lk + 0][lr] = av.x; As[lk + 1][lr] = av.y;
    As[lk + 2][lr] = av.z; As[lk + 3][lr] = av.w;
    *(float4*)&Bs[br][bn] = bv;
    __syncthreads();
    const int kn = (k0 + 16 < DIM) ? k0 + 16 : k0;   // safe prefetch addr
    av = *(const float4*)&A[(size_t)(m0 + lr) * DIM + kn + lk];
    bv = *(const float4*)&Wm[(size_t)(kn + br) * DIM + n0 + bn];
#pragma unroll
    for (int kk = 0; kk < 16; ++kk) {
      const float4 a4 = *(const float4*)&As[kk][ty * 4];
      const float4 b4 = *(const float4*)&Bs[kk][tx * 4];
      const float a[4] = {a4.x, a4.y, a4.z, a4.w};
      const float b[4] = {b4.x, b4.y, b4.z, b4.w};
#pragma unroll
      for (int i = 0; i < 4; ++i)
#pragma unroll
        for (int j = 0; j < 4; ++j) acc[i][j] = fmaf(a[i], b[j], acc[i][j]);
    }
    __syncthreads();
  }
#pragma unroll
  for (int i = 0; i < 4; ++i) {
    float4 o = {acc[i][0], acc[i][1], acc[i][2], acc[i][3]};
    *(float4*)&C[(size_t)(m0 + ty * 4 + i) * DIM + n0 + tx * 4] = o;
  }
}

// scores[(q*B_+b)*SEQ + s] = sum_e query[q,b,e] * cw[b,s,e]   (NT GEMM per batch)
__global__ __launch_bounds__(256) void kernel_scores(const float* __restrict__ Q,
                                                     const float* __restrict__ CW,
                                                     float* __restrict__ Sc) {
  __shared__ float As[16][68];   // As[k][q]
  __shared__ float Bs[16][68];   // Bs[k][s]
  const int b = blockIdx.z;
  const int tid = threadIdx.x;
  const int tx = tid & 15, ty = tid >> 4;
  const int q0 = blockIdx.y * 64, s0 = blockIdx.x * 64;

  const int lr = tid >> 2;
  const int lk = (tid & 3) * 4;

  const float* Aptr = Q + (size_t)q0 * (B_ * DIM) + (size_t)b * DIM;  // row stride B_*DIM
  const float* Bptr = CW + (size_t)b * SEQ * DIM + (size_t)s0 * DIM;  // row stride DIM

  float4 av = *(const float4*)&Aptr[(size_t)lr * (B_ * DIM) + lk];
  float4 bv = *(const float4*)&Bptr[(size_t)lr * DIM + lk];

  float acc[4][4] = {};
  for (int k0 = 0; k0 < DIM; k0 += 16) {
    As[lk + 0][lr] = av.x; As[lk + 1][lr] = av.y;
    As[lk + 2][lr] = av.z; As[lk + 3][lr] = av.w;
    Bs[lk + 0][lr] = bv.x; Bs[lk + 1][lr] = bv.y;
    Bs[lk + 2][lr] = bv.z; Bs[lk + 3][lr] = bv.w;
    __syncthreads();
    const int kn = (k0 + 16 < DIM) ? k0 + 16 : k0;
    av = *(const float4*)&Aptr[(size_t)lr * (B_ * DIM) + kn + lk];
    bv = *(const float4*)&Bptr[(size_t)lr * DIM + kn + lk];
#pragma unroll
    for (int kk = 0; kk < 16; ++kk) {
      const float4 a4 = *(const float4*)&As[kk][ty * 4];
      const float4 b4 = *(const float4*)&Bs[kk][tx * 4];
      const float a[4] = {a4.x, a4.y, a4.z, a4.w};
      const float b[4] = {b4.x, b4.y, b4.z, b4.w};
#pragma unroll
      for (int i = 0; i < 4; ++i)
#pragma unroll
        for (int j = 0; j < 4; ++j) acc[i][j] = fmaf(a[i], b[j], acc[i][j]);
    }
    __syncthreads();
  }
#pragma unroll
  for (int i = 0; i < 4; ++i) {
    float4 o = {acc[i][0], acc[i][1], acc[i][2], acc[i][3]};
    *(float4*)&Sc[((size_t)(q0 + ty * 4 + i) * B_ + b) * SEQ + s0 + tx * 4] = o;
  }
}

// in-place masked softmax over s for each row (q*B_+b); all-masked rows -> 0
// mask arrives as int32 (one int per position; nonzero = masked)
__global__ __launch_bounds__(256) void kernel_softmax(float* __restrict__ attn,
                                                      const int* __restrict__ mask) {
  const int row = blockIdx.x;       // q*B_ + b
  const int b = row & (B_ - 1);
  float* p = attn + (size_t)row * SEQ;
  const int* m = mask + (size_t)b * SEQ;
  const int t = threadIdx.x;

  float v[8];
  float mx = -INFINITY;
#pragma unroll
  for (int i = 0; i < 8; ++i) {
    const int s = t + i * 256;
    float x = p[s];
    x = m[s] ? -1e30f : x;
    v[i] = x;
    mx = fmaxf(mx, x);
  }
#pragma unroll
  for (int off = 32; off > 0; off >>= 1) mx = fmaxf(mx, __shfl_xor(mx, off));
  __shared__ float redmax[4];
  __shared__ float redsum[4];
  if ((t & 63) == 0) redmax[t >> 6] = mx;
  __syncthreads();
  mx = fmaxf(fmaxf(redmax[0], redmax[1]), fmaxf(redmax[2], redmax[3]));

  float sum = 0.f;
#pragma unroll
  for (int i = 0; i < 8; ++i) {
    v[i] = __expf(v[i] - mx);
    sum += v[i];
  }
#pragma unroll
  for (int off = 32; off > 0; off >>= 1) sum += __shfl_xor(sum, off);
  if ((t & 63) == 0) redsum[t >> 6] = sum;
  __syncthreads();
  sum = (redsum[0] + redsum[1]) + (redsum[2] + redsum[3]);

  const bool allmasked = (mx < -1e29f);
  const float inv = allmasked ? 0.f : 1.f / sum;
#pragma unroll
  for (int i = 0; i < 8; ++i) p[t + i * 256] = v[i] * inv;
}

// comp[(q*B_+b)*DIM + d] = sum_s attn[(q*B_+b)*SEQ + s] * context[b,s,d]
__global__ __launch_bounds__(256) void kernel_comp(const float* __restrict__ At,
                                                   const float* __restrict__ Ctx,
                                                   float* __restrict__ O) {
  __shared__ float As[16][68];   // As[s][q]
  __shared__ float Bs[16][68];   // Bs[s][d]
  const int b = blockIdx.z;
  const int tid = threadIdx.x;
  const int tx = tid & 15, ty = tid >> 4;
  const int q0 = blockIdx.y * 64, d0 = blockIdx.x * 64;

  const int lr = tid >> 2;
  const int lk = (tid & 3) * 4;
  const int br = tid >> 4;
  const int bn = (tid & 15) * 4;

  const float* Aptr = At + (size_t)q0 * (B_ * SEQ) + (size_t)b * SEQ;   // row stride B_*SEQ
  const float* Bptr = Ctx + (size_t)b * SEQ * DIM;                      // row stride DIM

  float4 av = *(const float4*)&Aptr[(size_t)lr * (B_ * SEQ) + lk];
  float4 bv = *(const float4*)&Bptr[(size_t)br * DIM + d0 + bn];

  float acc[4][4] = {};
  for (int k0 = 0; k0 < SEQ; k0 += 16) {
    As[lk + 0][lr] = av.x; As[lk + 1][lr] = av.y;
    As[lk + 2][lr] = av.z; As[lk + 3][lr] = av.w;
    *(float4*)&Bs[br][bn] = bv;
    __syncthreads();
    const int kn = (k0 + 16 < SEQ) ? k0 + 16 : k0;
    av = *(const float4*)&Aptr[(size_t)lr * (B_ * SEQ) + kn + lk];
    bv = *(const float4*)&Bptr[(size_t)(kn + br) * DIM + d0 + bn];
#pragma unroll
    for (int kk = 0; kk < 16; ++kk) {
      const float4 a4 = *(const float4*)&As[kk][ty * 4];
      const float4 b4 = *(const float4*)&Bs[kk][tx * 4];
      const float a[4] = {a4.x, a4.y, a4.z, a4.w};
      const float b[4] = {b4.x, b4.y, b4.z, b4.w};
#pragma unroll
      for (int i = 0; i < 4; ++i)
#pragma unroll
        for (int j = 0; j < 4; ++j) acc[i][j] = fmaf(a[i], b[j], acc[i][j]);
    }
    __syncthreads();
  }
#pragma unroll
  for (int i = 0; i < 4; ++i) {
    float4 o = {acc[i][0], acc[i][1], acc[i][2], acc[i][3]};
    *(float4*)&O[((size_t)(q0 + ty * 4 + i) * B_ + b) * DIM + d0 + tx * 4] = o;
  }
}

extern "C" void kernel_launch(void* const* d_in, const int* in_sizes, int n_in,
                              void* d_out, int out_size, void* d_ws, size_t ws_size,
                              hipStream_t stream) {
  const float* context = (const float*)d_in[0];          // [B, SEQ, DIM]
  const float* query   = (const float*)d_in[1];          // [SEQ, B, DIM]
  const float* W       = (const float*)d_in[2];          // [DIM, DIM]
  const int*   mask    = (const int*)d_in[3];            // [B, SEQ] bool -> int32

  float* attn = (float*)d_out;                            // [SEQ, B, SEQ]
  float* comp = attn + (size_t)SEQ * B_ * SEQ;            // [SEQ, B, DIM]
  float* cw   = (float*)d_ws;                             // [B, SEQ, DIM] = 128 MiB

  // 1) cw = context @ W
  kernel_cw<<<dim3(DIM / 64, (B_ * SEQ) / 64), 256, 0, stream>>>(context, W, cw);
  // 2) scores -> attn region of d_out, [q,b,s] layout
  kernel_scores<<<dim3(SEQ / 64, SEQ / 64, B_), 256, 0, stream>>>(query, cw, attn);
  // 3) masked softmax in place
  kernel_softmax<<<dim3(SEQ * B_), 256, 0, stream>>>(attn, mask);
  // 4) composition = attn @ context
  kernel_comp<<<dim3(DIM / 64, SEQ / 64, B_), 256, 0, stream>>>(attn, context, comp);
}

// Round 3
// 1762.971 us; speedup vs baseline: 2.3934x; 2.3934x over previous
//
#include <hip/hip_runtime.h>
#include <cmath>

#define B_  16
#define SEQ 2048
#define DIM 1024
#define LDST 40              // LDS row stride in bf16 elems (80 B: 16B-aligned, ~2-way banks)

typedef short  short8 __attribute__((ext_vector_type(8)));
typedef float  f32x4  __attribute__((ext_vector_type(4)));

__device__ __forceinline__ unsigned short f2bf(float x) {
  unsigned u = __builtin_bit_cast(unsigned, x);
  return (unsigned short)((u + 0x7fffu + ((u >> 16) & 1u)) >> 16);   // RNE
}
__device__ __forceinline__ float bf2f(unsigned short h) {
  unsigned u = ((unsigned)h) << 16;
  return __builtin_bit_cast(float, u);
}

// ---------------------------------------------------------------------------
// G1: z[r][d] = sum_e query[r][e] * W[d][e],  r = q*B_+b (flat rows of query)
// M=32768, N=1024, K=1024. bf16x2, 3 products. Output: z_hi/z_lo bf16.
// ---------------------------------------------------------------------------
__global__ __launch_bounds__(256) void g1_z(const float* __restrict__ Q,
                                            const float* __restrict__ W,
                                            unsigned short* __restrict__ zhi,
                                            unsigned short* __restrict__ zlo) {
  __shared__ unsigned short Ah[128 * LDST], Al[128 * LDST];
  __shared__ unsigned short Bh[128 * LDST], Bl[128 * LDST];
  const int tid = threadIdx.x;
  const int m0 = blockIdx.y * 128, n0 = blockIdx.x * 128;
  const int wave = tid >> 6, lane = tid & 63;
  const int wm = (wave >> 1) * 64, wn = (wave & 1) * 64;
  const int rl = tid & 127;

  const float* srow = (tid < 128) ? Q + (size_t)(m0 + rl) * DIM
                                  : W + (size_t)(n0 + rl) * DIM;
  unsigned short* th = (tid < 128) ? Ah : Bh;
  unsigned short* tl = (tid < 128) ? Al : Bl;

  f32x4 acc[4][4];
#pragma unroll
  for (int i = 0; i < 4; ++i)
#pragma unroll
    for (int j = 0; j < 4; ++j) acc[i][j] = (f32x4){0.f, 0.f, 0.f, 0.f};

  for (int kc = 0; kc < DIM; kc += 32) {
    float4 fv[8];
#pragma unroll
    for (int j = 0; j < 8; ++j) fv[j] = *(const float4*)&srow[kc + j * 4];
    __syncthreads();   // previous tile fully consumed
    short8 hv[4], lv[4];
#pragma unroll
    for (int j = 0; j < 8; ++j) {
      const float x[4] = {fv[j].x, fv[j].y, fv[j].z, fv[j].w};
#pragma unroll
      for (int c = 0; c < 4; ++c) {
        unsigned short h = f2bf(x[c]);
        unsigned short l = f2bf(x[c] - bf2f(h));
        hv[j >> 1][(j & 1) * 4 + c] = (short)h;
        lv[j >> 1][(j & 1) * 4 + c] = (short)l;
      }
    }
#pragma unroll
    for (int j = 0; j < 4; ++j) {
      *(short8*)&th[rl * LDST + j * 8] = hv[j];
      *(short8*)&tl[rl * LDST + j * 8] = lv[j];
    }
    __syncthreads();

    short8 ah[4], al[4], bh[4], bl[4];
#pragma unroll
    for (int f = 0; f < 4; ++f) {
      const int ao = (wm + f * 16 + (lane & 15)) * LDST + (lane >> 4) * 8;
      const int bo = (wn + f * 16 + (lane & 15)) * LDST + (lane >> 4) * 8;
      ah[f] = *(const short8*)&Ah[ao];  al[f] = *(const short8*)&Al[ao];
      bh[f] = *(const short8*)&Bh[bo];  bl[f] = *(const short8*)&Bl[bo];
    }
#pragma unroll
    for (int i = 0; i < 4; ++i)
#pragma unroll
      for (int j = 0; j < 4; ++j) {
        acc[i][j] = __builtin_amdgcn_mfma_f32_16x16x32_bf16(ah[i], bh[j], acc[i][j], 0, 0, 0);
        acc[i][j] = __builtin_amdgcn_mfma_f32_16x16x32_bf16(al[i], bh[j], acc[i][j], 0, 0, 0);
        acc[i][j] = __builtin_amdgcn_mfma_f32_16x16x32_bf16(ah[i], bl[j], acc[i][j], 0, 0, 0);
      }
  }
#pragma unroll
  for (int i = 0; i < 4; ++i)
#pragma unroll
    for (int j = 0; j < 4; ++j)
#pragma unroll
      for (int r = 0; r < 4; ++r) {
        const int row = m0 + wm + i * 16 + (lane >> 4) * 4 + r;
        const int col = n0 + wn + j * 16 + (lane & 15);
        const float v = acc[i][j][r];
        const unsigned short h = f2bf(v);
        zhi[(size_t)row * DIM + col] = h;
        zlo[(size_t)row * DIM + col] = f2bf(v - bf2f(h));
      }
}

// ---------------------------------------------------------------------------
// G2: scores[q][b][s] = sum_d z[q*B_+b][d] * ctx[b][s][d]. Per-batch NT GEMM,
// M=2048(q), N=2048(s), K=1024(d). A = z hi/lo bf16 (copy), B = ctx f32 (split).
// ---------------------------------------------------------------------------
__global__ __launch_bounds__(256) void g2_scores(const unsigned short* __restrict__ zhi,
                                                 const unsigned short* __restrict__ zlo,
                                                 const float* __restrict__ Ctx,
                                                 float* __restrict__ Sc) {
  __shared__ unsigned short Ah[128 * LDST], Al[128 * LDST];
  __shared__ unsigned short Bh[128 * LDST], Bl[128 * LDST];
  const int b = blockIdx.z;
  const int tid = threadIdx.x;
  const int q0 = blockIdx.y * 128, s0 = blockIdx.x * 128;
  const int wave = tid >> 6, lane = tid & 63;
  const int wm = (wave >> 1) * 64, wn = (wave & 1) * 64;
  const int rl = tid & 127;

  const size_t zrow = (size_t)(q0 + rl) * B_ + b;     // flat z row
  const float* crow = Ctx + ((size_t)b * SEQ + (s0 + rl)) * DIM;

  f32x4 acc[4][4];
#pragma unroll
  for (int i = 0; i < 4; ++i)
#pragma unroll
    for (int j = 0; j < 4; ++j) acc[i][j] = (f32x4){0.f, 0.f, 0.f, 0.f};

  for (int kc = 0; kc < DIM; kc += 32) {
    if (tid < 128) {
      int4 h4[2], l4[2];
#pragma unroll
      for (int j = 0; j < 2; ++j) {
        h4[j] = *(const int4*)&zhi[zrow * DIM + kc + j * 8 + 0];
        l4[j] = *(const int4*)&zlo[zrow * DIM + kc + j * 8 + 0];
      }
      int4 h4b[2], l4b[2];
#pragma unroll
      for (int j = 0; j < 2; ++j) {
        h4b[j] = *(const int4*)&zhi[zrow * DIM + kc + 16 + j * 8];
        l4b[j] = *(const int4*)&zlo[zrow * DIM + kc + 16 + j * 8];
      }
      __syncthreads();
      *(int4*)&Ah[rl * LDST + 0]  = h4[0];  *(int4*)&Ah[rl * LDST + 8]  = h4[1];
      *(int4*)&Ah[rl * LDST + 16] = h4b[0]; *(int4*)&Ah[rl * LDST + 24] = h4b[1];
      *(int4*)&Al[rl * LDST + 0]  = l4[0];  *(int4*)&Al[rl * LDST + 8]  = l4[1];
      *(int4*)&Al[rl * LDST + 16] = l4b[0]; *(int4*)&Al[rl * LDST + 24] = l4b[1];
    } else {
      float4 fv[8];
#pragma unroll
      for (int j = 0; j < 8; ++j) fv[j] = *(const float4*)&crow[kc + j * 4];
      __syncthreads();
      short8 hv[4], lv[4];
#pragma unroll
      for (int j = 0; j < 8; ++j) {
        const float x[4] = {fv[j].x, fv[j].y, fv[j].z, fv[j].w};
#pragma unroll
        for (int c = 0; c < 4; ++c) {
          unsigned short h = f2bf(x[c]);
          unsigned short l = f2bf(x[c] - bf2f(h));
          hv[j >> 1][(j & 1) * 4 + c] = (short)h;
          lv[j >> 1][(j & 1) * 4 + c] = (short)l;
        }
      }
#pragma unroll
      for (int j = 0; j < 4; ++j) {
        *(short8*)&Bh[rl * LDST + j * 8] = hv[j];
        *(short8*)&Bl[rl * LDST + j * 8] = lv[j];
      }
    }
    __syncthreads();

    short8 ah[4], al[4], bh[4], bl[4];
#pragma unroll
    for (int f = 0; f < 4; ++f) {
      const int ao = (wm + f * 16 + (lane & 15)) * LDST + (lane >> 4) * 8;
      const int bo = (wn + f * 16 + (lane & 15)) * LDST + (lane >> 4) * 8;
      ah[f] = *(const short8*)&Ah[ao];  al[f] = *(const short8*)&Al[ao];
      bh[f] = *(const short8*)&Bh[bo];  bl[f] = *(const short8*)&Bl[bo];
    }
#pragma unroll
    for (int i = 0; i < 4; ++i)
#pragma unroll
      for (int j = 0; j < 4; ++j) {
        acc[i][j] = __builtin_amdgcn_mfma_f32_16x16x32_bf16(ah[i], bh[j], acc[i][j], 0, 0, 0);
        acc[i][j] = __builtin_amdgcn_mfma_f32_16x16x32_bf16(al[i], bh[j], acc[i][j], 0, 0, 0);
        acc[i][j] = __builtin_amdgcn_mfma_f32_16x16x32_bf16(ah[i], bl[j], acc[i][j], 0, 0, 0);
      }
  }
#pragma unroll
  for (int i = 0; i < 4; ++i)
#pragma unroll
    for (int j = 0; j < 4; ++j)
#pragma unroll
      for (int r = 0; r < 4; ++r) {
        const int q = q0 + wm + i * 16 + (lane >> 4) * 4 + r;
        const int s = s0 + wn + j * 16 + (lane & 15);
        Sc[((size_t)q * B_ + b) * SEQ + s] = acc[i][j][r];
      }
}

// ---------------------------------------------------------------------------
// softmax: in-place on d_out attn region, plus bf16 copy to ws[b][q][s]
// ---------------------------------------------------------------------------
__global__ __launch_bounds__(256) void kernel_softmax(float* __restrict__ attn,
                                                      const int* __restrict__ mask,
                                                      unsigned short* __restrict__ attnb) {
  const int row = blockIdx.x;       // q*B_ + b
  const int b = row & (B_ - 1);
  const int q = row >> 4;
  float* p = attn + (size_t)row * SEQ;
  const int* m = mask + (size_t)b * SEQ;
  unsigned short* pb = attnb + ((size_t)b * SEQ + q) * SEQ;
  const int t = threadIdx.x;

  float v[8];
  float mx = -INFINITY;
#pragma unroll
  for (int i = 0; i < 8; ++i) {
    const int s = t + i * 256;
    float x = p[s];
    x = m[s] ? -1e30f : x;
    v[i] = x;
    mx = fmaxf(mx, x);
  }
#pragma unroll
  for (int off = 32; off > 0; off >>= 1) mx = fmaxf(mx, __shfl_xor(mx, off));
  __shared__ float redmax[4];
  __shared__ float redsum[4];
  if ((t & 63) == 0) redmax[t >> 6] = mx;
  __syncthreads();
  mx = fmaxf(fmaxf(redmax[0], redmax[1]), fmaxf(redmax[2], redmax[3]));

  float sum = 0.f;
#pragma unroll
  for (int i = 0; i < 8; ++i) {
    v[i] = __expf(v[i] - mx);
    sum += v[i];
  }
#pragma unroll
  for (int off = 32; off > 0; off >>= 1) sum += __shfl_xor(sum, off);
  if ((t & 63) == 0) redsum[t >> 6] = sum;
  __syncthreads();
  sum = (redsum[0] + redsum[1]) + (redsum[2] + redsum[3]);

  const bool allmasked = (mx < -1e29f);
  const float inv = allmasked ? 0.f : 1.f / sum;
#pragma unroll
  for (int i = 0; i < 8; ++i) {
    const float a = v[i] * inv;
    p[t + i * 256] = a;
    pb[t + i * 256] = f2bf(a);
  }
}

// ---------------------------------------------------------------------------
// G3: comp[q][b][d] = sum_s attn[q][b][s] * ctx[b][s][d]. Per-batch GEMM,
// M=2048(q), N=1024(d), K=2048(s). A = attn bf16 ws (rows), B = ctx f32
// transposed+converted into LDS [d][s]. Single bf16 product.
// ---------------------------------------------------------------------------
__global__ __launch_bounds__(256) void g3_comp(const unsigned short* __restrict__ attnb,
                                               const float* __restrict__ Ctx,
                                               float* __restrict__ Out) {
  __shared__ unsigned short As[128 * LDST], Bs[128 * LDST];
  const int b = blockIdx.z;
  const int tid = threadIdx.x;
  const int q0 = blockIdx.y * 128, d0 = blockIdx.x * 128;
  const int wave = tid >> 6, lane = tid & 63;
  const int wm = (wave >> 1) * 64, wn = (wave & 1) * 64;

  const int arow = tid >> 1, ak = (tid & 1) * 16;    // A staging
  const int dl = tid & 127, sh = tid >> 7;           // B staging

  const unsigned short* asrc = attnb + ((size_t)b * SEQ + (q0 + arow)) * SEQ + ak;
  const float* bsrc = Ctx + (size_t)b * SEQ * DIM + d0 + dl;

  f32x4 acc[4][4];
#pragma unroll
  for (int i = 0; i < 4; ++i)
#pragma unroll
    for (int j = 0; j < 4; ++j) acc[i][j] = (f32x4){0.f, 0.f, 0.f, 0.f};

  for (int kc = 0; kc < SEQ; kc += 32) {
    int4 a0 = *(const int4*)&asrc[kc];
    int4 a1 = *(const int4*)&asrc[kc + 8];
    float bf[16];
#pragma unroll
    for (int i = 0; i < 16; ++i)
      bf[i] = bsrc[(size_t)(kc + sh * 16 + i) * DIM];
    __syncthreads();
    *(int4*)&As[arow * LDST + ak]     = a0;
    *(int4*)&As[arow * LDST + ak + 8] = a1;
    short8 bv[2];
#pragma unroll
    for (int i = 0; i < 16; ++i) bv[i >> 3][i & 7] = (short)f2bf(bf[i]);
    *(short8*)&Bs[dl * LDST + sh * 16]     = bv[0];
    *(short8*)&Bs[dl * LDST + sh * 16 + 8] = bv[1];
    __syncthreads();

    short8 af[4], bfr[4];
#pragma unroll
    for (int f = 0; f < 4; ++f) {
      af[f]  = *(const short8*)&As[(wm + f * 16 + (lane & 15)) * LDST + (lane >> 4) * 8];
      bfr[f] = *(const short8*)&Bs[(wn + f * 16 + (lane & 15)) * LDST + (lane >> 4) * 8];
    }
#pragma unroll
    for (int i = 0; i < 4; ++i)
#pragma unroll
      for (int j = 0; j < 4; ++j)
        acc[i][j] = __builtin_amdgcn_mfma_f32_16x16x32_bf16(af[i], bfr[j], acc[i][j], 0, 0, 0);
  }
#pragma unroll
  for (int i = 0; i < 4; ++i)
#pragma unroll
    for (int j = 0; j < 4; ++j)
#pragma unroll
      for (int r = 0; r < 4; ++r) {
        const int q = q0 + wm + i * 16 + (lane >> 4) * 4 + r;
        const int d = d0 + wn + j * 16 + (lane & 15);
        Out[((size_t)q * B_ + b) * DIM + d] = acc[i][j][r];
      }
}

extern "C" void kernel_launch(void* const* d_in, const int* in_sizes, int n_in,
                              void* d_out, int out_size, void* d_ws, size_t ws_size,
                              hipStream_t stream) {
  const float* context = (const float*)d_in[0];   // [B, SEQ, DIM]
  const float* query   = (const float*)d_in[1];   // [SEQ, B, DIM]
  const float* W       = (const float*)d_in[2];   // [DIM, DIM]
  const int*   mask    = (const int*)d_in[3];     // [B, SEQ] bool->int32

  float* attn = (float*)d_out;                     // [SEQ, B, SEQ]
  float* comp = attn + (size_t)SEQ * B_ * SEQ;     // [SEQ, B, DIM]

  unsigned short* zhi   = (unsigned short*)d_ws;                    // [32768,1024] bf16 = 64 MiB
  unsigned short* zlo   = zhi + (size_t)SEQ * B_ * DIM;             // 64 MiB
  unsigned short* attnb = (unsigned short*)d_ws;                    // [b][q][s] bf16, reuses z after G2

  // 1) z = W @ query (flat rows), bf16x2 output
  g1_z<<<dim3(DIM / 128, (SEQ * B_) / 128), 256, 0, stream>>>(query, W, zhi, zlo);
  // 2) scores = z . ctx^T (per batch), 3-product bf16x2, f32 out -> d_out
  g2_scores<<<dim3(SEQ / 128, SEQ / 128, B_), 256, 0, stream>>>(zhi, zlo, context, attn);
  // 3) masked softmax in place + bf16 copy (overwrites z region)
  kernel_softmax<<<dim3(SEQ * B_), 256, 0, stream>>>(attn, mask, attnb);
  // 4) comp = attn @ ctx, plain bf16
  g3_comp<<<dim3(DIM / 128, SEQ / 128, B_), 256, 0, stream>>>(attnb, context, comp);
}

// Round 5
// 1196.509 us; speedup vs baseline: 3.5266x; 1.4734x over previous
//
#include <hip/hip_runtime.h>
#include <cmath>

#define B_  16
#define SEQ 2048
#define DIM 1024
#define LDST 40              // legacy stride for g1/g3 LDS tiles

typedef short  short8 __attribute__((ext_vector_type(8)));
typedef float  f32x4  __attribute__((ext_vector_type(4)));

__device__ __forceinline__ unsigned short f2bf(float x) {
  unsigned u = __builtin_bit_cast(unsigned, x);
  return (unsigned short)((u + 0x7fffu + ((u >> 16) & 1u)) >> 16);   // RNE
}
__device__ __forceinline__ float bf2f(unsigned short h) {
  unsigned u = ((unsigned)h) << 16;
  return __builtin_bit_cast(float, u);
}

// async global->LDS, 16B per lane; LDS dest = wave-uniform base + lane*16
__device__ __forceinline__ void gl16(const void* g, void* l) {
  __builtin_amdgcn_global_load_lds(
      (const __attribute__((address_space(1))) void*)g,
      (__attribute__((address_space(3))) void*)l, 16, 0, 0);
}

// ---------------------------------------------------------------------------
// cvt_ctx: ctx f32 -> ctx_hi/ctx_lo bf16 planes (written into d_out comp region)
// ---------------------------------------------------------------------------
__global__ __launch_bounds__(256) void cvt_ctx(const float* __restrict__ X,
                                               unsigned short* __restrict__ hi,
                                               unsigned short* __restrict__ lo) {
  const size_t N8 = (size_t)B_ * SEQ * DIM / 8;
  for (size_t i = (size_t)blockIdx.x * 256 + threadIdx.x; i < N8;
       i += (size_t)gridDim.x * 256) {
    const size_t base = i * 8;
    float4 a = *(const float4*)&X[base];
    float4 c = *(const float4*)&X[base + 4];
    const float xs[8] = {a.x, a.y, a.z, a.w, c.x, c.y, c.z, c.w};
    short8 h, l;
#pragma unroll
    for (int j = 0; j < 8; ++j) {
      unsigned short hh = f2bf(xs[j]);
      h[j] = (short)hh;
      l[j] = (short)f2bf(xs[j] - bf2f(hh));
    }
    *(short8*)&hi[base] = h;
    *(short8*)&lo[base] = l;
  }
}

// ---------------------------------------------------------------------------
// G1: z[r][d] = sum_e query[r][e] * W[d][e],  r = q*B_+b  (unchanged from R3)
// ---------------------------------------------------------------------------
__global__ __launch_bounds__(256) void g1_z(const float* __restrict__ Q,
                                            const float* __restrict__ W,
                                            unsigned short* __restrict__ zhi,
                                            unsigned short* __restrict__ zlo) {
  __shared__ unsigned short Ah[128 * LDST], Al[128 * LDST];
  __shared__ unsigned short Bh[128 * LDST], Bl[128 * LDST];
  const int tid = threadIdx.x;
  const int m0 = blockIdx.y * 128, n0 = blockIdx.x * 128;
  const int wave = tid >> 6, lane = tid & 63;
  const int wm = (wave >> 1) * 64, wn = (wave & 1) * 64;
  const int rl = tid & 127;

  const float* srow = (tid < 128) ? Q + (size_t)(m0 + rl) * DIM
                                  : W + (size_t)(n0 + rl) * DIM;
  unsigned short* th = (tid < 128) ? Ah : Bh;
  unsigned short* tl = (tid < 128) ? Al : Bl;

  f32x4 acc[4][4];
#pragma unroll
  for (int i = 0; i < 4; ++i)
#pragma unroll
    for (int j = 0; j < 4; ++j) acc[i][j] = (f32x4){0.f, 0.f, 0.f, 0.f};

  for (int kc = 0; kc < DIM; kc += 32) {
    float4 fv[8];
#pragma unroll
    for (int j = 0; j < 8; ++j) fv[j] = *(const float4*)&srow[kc + j * 4];
    __syncthreads();
    short8 hv[4], lv[4];
#pragma unroll
    for (int j = 0; j < 8; ++j) {
      const float x[4] = {fv[j].x, fv[j].y, fv[j].z, fv[j].w};
#pragma unroll
      for (int c = 0; c < 4; ++c) {
        unsigned short h = f2bf(x[c]);
        unsigned short l = f2bf(x[c] - bf2f(h));
        hv[j >> 1][(j & 1) * 4 + c] = (short)h;
        lv[j >> 1][(j & 1) * 4 + c] = (short)l;
      }
    }
#pragma unroll
    for (int j = 0; j < 4; ++j) {
      *(short8*)&th[rl * LDST + j * 8] = hv[j];
      *(short8*)&tl[rl * LDST + j * 8] = lv[j];
    }
    __syncthreads();

    short8 ah[4], al[4], bh[4], bl[4];
#pragma unroll
    for (int f = 0; f < 4; ++f) {
      const int ao = (wm + f * 16 + (lane & 15)) * LDST + (lane >> 4) * 8;
      const int bo = (wn + f * 16 + (lane & 15)) * LDST + (lane >> 4) * 8;
      ah[f] = *(const short8*)&Ah[ao];  al[f] = *(const short8*)&Al[ao];
      bh[f] = *(const short8*)&Bh[bo];  bl[f] = *(const short8*)&Bl[bo];
    }
#pragma unroll
    for (int i = 0; i < 4; ++i)
#pragma unroll
      for (int j = 0; j < 4; ++j) {
        acc[i][j] = __builtin_amdgcn_mfma_f32_16x16x32_bf16(ah[i], bh[j], acc[i][j], 0, 0, 0);
        acc[i][j] = __builtin_amdgcn_mfma_f32_16x16x32_bf16(al[i], bh[j], acc[i][j], 0, 0, 0);
        acc[i][j] = __builtin_amdgcn_mfma_f32_16x16x32_bf16(ah[i], bl[j], acc[i][j], 0, 0, 0);
      }
  }
#pragma unroll
  for (int i = 0; i < 4; ++i)
#pragma unroll
    for (int j = 0; j < 4; ++j)
#pragma unroll
      for (int r = 0; r < 4; ++r) {
        const int row = m0 + wm + i * 16 + (lane >> 4) * 4 + r;
        const int col = n0 + wn + j * 16 + (lane & 15);
        const float v = acc[i][j][r];
        const unsigned short h = f2bf(v);
        zhi[(size_t)row * DIM + col] = h;
        zlo[(size_t)row * DIM + col] = f2bf(v - bf2f(h));
      }
}

// ---------------------------------------------------------------------------
// G2 (rebuilt, m97-style): scores[q][b][s] = sum_d z[q*B_+b][d] * ctx[b][s][d]
// A-operand = ctx s-rows (M=s), B-operand = z q-rows (N=q)  ->  D rows = s
// (contiguous output dim) -> float4 nontemporal stores.
// All 4 tiles staged with global_load_lds(16B); BK=32 => 64B LDS rows =>
// conflict-free fragment reads, linear layout (no swizzle needed).
// ---------------------------------------------------------------------------
#define G2GRID (16 * 16 * B_)
__global__ __launch_bounds__(256) void g2_scores(const unsigned short* __restrict__ zhi,
                                                 const unsigned short* __restrict__ zlo,
                                                 const unsigned short* __restrict__ chi,
                                                 const unsigned short* __restrict__ clo,
                                                 float* __restrict__ Sc) {
  __shared__ unsigned short Sh[128 * 32], Sl[128 * 32];   // ctx tiles (s-rows)
  __shared__ unsigned short Qh[128 * 32], Ql[128 * 32];   // z tiles (q-rows)
  const int tid = threadIdx.x, lane = tid & 63, wave = tid >> 6;

  // bijective XCD-chunked swizzle (nwg = 4096, %8 == 0)
  const int lin = blockIdx.x;
  const int swz = (lin & 7) * (G2GRID / 8) + (lin >> 3);
  const int s0 = (swz & 15) * 128;
  const int q0 = ((swz >> 4) & 15) * 128;
  const int b  = swz >> 8;

  const int wm = (wave >> 1) * 64;   // s-offset of this wave's tile
  const int wn = (wave & 1) * 64;    // q-offset

  const int r_sub = lane >> 2;            // row within 16-row gload chunk
  const int c_sub = (lane & 3) * 8;       // short offset within 64B row

  f32x4 acc[4][4];
#pragma unroll
  for (int i = 0; i < 4; ++i)
#pragma unroll
    for (int j = 0; j < 4; ++j) acc[i][j] = (f32x4){0.f, 0.f, 0.f, 0.f};

  for (int kc = 0; kc < DIM; kc += 32) {
    // each wave stages one 8KB tile: 8 x (64 lanes x 16B)
    if (wave == 0) {
#pragma unroll
      for (int it = 0; it < 8; ++it)
        gl16(&chi[((size_t)b * SEQ + s0 + it * 16 + r_sub) * DIM + kc + c_sub], &Sh[it * 512]);
    } else if (wave == 1) {
#pragma unroll
      for (int it = 0; it < 8; ++it)
        gl16(&clo[((size_t)b * SEQ + s0 + it * 16 + r_sub) * DIM + kc + c_sub], &Sl[it * 512]);
    } else if (wave == 2) {
#pragma unroll
      for (int it = 0; it < 8; ++it)
        gl16(&zhi[((size_t)(q0 + it * 16 + r_sub) * B_ + b) * DIM + kc + c_sub], &Qh[it * 512]);
    } else {
#pragma unroll
      for (int it = 0; it < 8; ++it)
        gl16(&zlo[((size_t)(q0 + it * 16 + r_sub) * B_ + b) * DIM + kc + c_sub], &Ql[it * 512]);
    }
    __syncthreads();   // compiler drains vmcnt before barrier

    const int fo = lane & 15, fk = (lane >> 4) * 8;
    short8 sh_[4], sl_[4], qh_[4], ql_[4];
#pragma unroll
    for (int f = 0; f < 4; ++f) {
      const int so = (wm + f * 16 + fo) * 32 + fk;
      const int qo = (wn + f * 16 + fo) * 32 + fk;
      sh_[f] = *(const short8*)&Sh[so];  sl_[f] = *(const short8*)&Sl[so];
      qh_[f] = *(const short8*)&Qh[qo];  ql_[f] = *(const short8*)&Ql[qo];
    }
#pragma unroll
    for (int i = 0; i < 4; ++i)
#pragma unroll
      for (int j = 0; j < 4; ++j) {
        acc[i][j] = __builtin_amdgcn_mfma_f32_16x16x32_bf16(sh_[i], qh_[j], acc[i][j], 0, 0, 0);
        acc[i][j] = __builtin_amdgcn_mfma_f32_16x16x32_bf16(sl_[i], qh_[j], acc[i][j], 0, 0, 0);
        acc[i][j] = __builtin_amdgcn_mfma_f32_16x16x32_bf16(sh_[i], ql_[j], acc[i][j], 0, 0, 0);
      }
    __syncthreads();
  }

  // D[m=s][n=q]: lane holds col q = lane&15, rows s = (lane>>4)*4 + r (contiguous)
#pragma unroll
  for (int i = 0; i < 4; ++i)
#pragma unroll
    for (int j = 0; j < 4; ++j) {
      const int s = s0 + wm + i * 16 + (lane >> 4) * 4;
      const int q = q0 + wn + j * 16 + (lane & 15);
      f32x4 v = {acc[i][j][0], acc[i][j][1], acc[i][j][2], acc[i][j][3]};
      __builtin_nontemporal_store(v, (f32x4*)&Sc[((size_t)q * B_ + b) * SEQ + s]);
    }
}

// ---------------------------------------------------------------------------
// softmax: in-place on d_out attn region, plus bf16 copy to ws[b][q][s]
// ---------------------------------------------------------------------------
__global__ __launch_bounds__(256) void kernel_softmax(float* __restrict__ attn,
                                                      const int* __restrict__ mask,
                                                      unsigned short* __restrict__ attnb) {
  const int row = blockIdx.x;       // q*B_ + b
  const int b = row & (B_ - 1);
  const int q = row >> 4;
  float* p = attn + (size_t)row * SEQ;
  const int* m = mask + (size_t)b * SEQ;
  unsigned short* pb = attnb + ((size_t)b * SEQ + q) * SEQ;
  const int t = threadIdx.x;

  float v[8];
  float mx = -INFINITY;
#pragma unroll
  for (int i = 0; i < 8; ++i) {
    const int s = t + i * 256;
    float x = p[s];
    x = m[s] ? -1e30f : x;
    v[i] = x;
    mx = fmaxf(mx, x);
  }
#pragma unroll
  for (int off = 32; off > 0; off >>= 1) mx = fmaxf(mx, __shfl_xor(mx, off));
  __shared__ float redmax[4];
  __shared__ float redsum[4];
  if ((t & 63) == 0) redmax[t >> 6] = mx;
  __syncthreads();
  mx = fmaxf(fmaxf(redmax[0], redmax[1]), fmaxf(redmax[2], redmax[3]));

  float sum = 0.f;
#pragma unroll
  for (int i = 0; i < 8; ++i) {
    v[i] = __expf(v[i] - mx);
    sum += v[i];
  }
#pragma unroll
  for (int off = 32; off > 0; off >>= 1) sum += __shfl_xor(sum, off);
  if ((t & 63) == 0) redsum[t >> 6] = sum;
  __syncthreads();
  sum = (redsum[0] + redsum[1]) + (redsum[2] + redsum[3]);

  const bool allmasked = (mx < -1e29f);
  const float inv = allmasked ? 0.f : 1.f / sum;
#pragma unroll
  for (int i = 0; i < 8; ++i) {
    const float a = v[i] * inv;
    p[t + i * 256] = a;
    pb[t + i * 256] = f2bf(a);
  }
}

// ---------------------------------------------------------------------------
// G3: comp[q][b][d] = sum_s attn[q][b][s] * ctx[b][s][d]  (unchanged from R3)
// ---------------------------------------------------------------------------
__global__ __launch_bounds__(256) void g3_comp(const unsigned short* __restrict__ attnb,
                                               const float* __restrict__ Ctx,
                                               float* __restrict__ Out) {
  __shared__ unsigned short As[128 * LDST], Bs[128 * LDST];
  const int b = blockIdx.z;
  const int tid = threadIdx.x;
  const int q0 = blockIdx.y * 128, d0 = blockIdx.x * 128;
  const int wave = tid >> 6, lane = tid & 63;
  const int wm = (wave >> 1) * 64, wn = (wave & 1) * 64;

  const int arow = tid >> 1, ak = (tid & 1) * 16;
  const int dl = tid & 127, sh = tid >> 7;

  const unsigned short* asrc = attnb + ((size_t)b * SEQ + (q0 + arow)) * SEQ + ak;
  const float* bsrc = Ctx + (size_t)b * SEQ * DIM + d0 + dl;

  f32x4 acc[4][4];
#pragma unroll
  for (int i = 0; i < 4; ++i)
#pragma unroll
    for (int j = 0; j < 4; ++j) acc[i][j] = (f32x4){0.f, 0.f, 0.f, 0.f};

  for (int kc = 0; kc < SEQ; kc += 32) {
    int4 a0 = *(const int4*)&asrc[kc];
    int4 a1 = *(const int4*)&asrc[kc + 8];
    float bf[16];
#pragma unroll
    for (int i = 0; i < 16; ++i)
      bf[i] = bsrc[(size_t)(kc + sh * 16 + i) * DIM];
    __syncthreads();
    *(int4*)&As[arow * LDST + ak]     = a0;
    *(int4*)&As[arow * LDST + ak + 8] = a1;
    short8 bv[2];
#pragma unroll
    for (int i = 0; i < 16; ++i) bv[i >> 3][i & 7] = (short)f2bf(bf[i]);
    *(short8*)&Bs[dl * LDST + sh * 16]     = bv[0];
    *(short8*)&Bs[dl * LDST + sh * 16 + 8] = bv[1];
    __syncthreads();

    short8 af[4], bfr[4];
#pragma unroll
    for (int f = 0; f < 4; ++f) {
      af[f]  = *(const short8*)&As[(wm + f * 16 + (lane & 15)) * LDST + (lane >> 4) * 8];
      bfr[f] = *(const short8*)&Bs[(wn + f * 16 + (lane & 15)) * LDST + (lane >> 4) * 8];
    }
#pragma unroll
    for (int i = 0; i < 4; ++i)
#pragma unroll
      for (int j = 0; j < 4; ++j)
        acc[i][j] = __builtin_amdgcn_mfma_f32_16x16x32_bf16(af[i], bfr[j], acc[i][j], 0, 0, 0);
  }
#pragma unroll
  for (int i = 0; i < 4; ++i)
#pragma unroll
    for (int j = 0; j < 4; ++j)
#pragma unroll
      for (int r = 0; r < 4; ++r) {
        const int q = q0 + wm + i * 16 + (lane >> 4) * 4 + r;
        const int d = d0 + wn + j * 16 + (lane & 15);
        Out[((size_t)q * B_ + b) * DIM + d] = acc[i][j][r];
      }
}

extern "C" void kernel_launch(void* const* d_in, const int* in_sizes, int n_in,
                              void* d_out, int out_size, void* d_ws, size_t ws_size,
                              hipStream_t stream) {
  const float* context = (const float*)d_in[0];   // [B, SEQ, DIM]
  const float* query   = (const float*)d_in[1];   // [SEQ, B, DIM]
  const float* W       = (const float*)d_in[2];   // [DIM, DIM]
  const int*   mask    = (const int*)d_in[3];     // [B, SEQ] bool->int32

  float* attn = (float*)d_out;                     // [SEQ, B, SEQ]  (256 MiB)
  float* comp = attn + (size_t)SEQ * B_ * SEQ;     // [SEQ, B, DIM]  (128 MiB)

  // ctx bf16 hi/lo planes live in the comp region until G3 overwrites it
  unsigned short* chi = (unsigned short*)comp;                     // 64 MiB
  unsigned short* clo = chi + (size_t)B_ * SEQ * DIM;              // 64 MiB

  unsigned short* zhi   = (unsigned short*)d_ws;                   // 64 MiB
  unsigned short* zlo   = zhi + (size_t)SEQ * B_ * DIM;            // 64 MiB
  unsigned short* attnb = (unsigned short*)d_ws;                   // reuses z after G2

  // 0) ctx -> bf16 hi/lo (into comp region; dead until G3)
  cvt_ctx<<<dim3(4096), 256, 0, stream>>>(context, chi, clo);
  // 1) z = W @ query (flat rows), bf16x2 output
  g1_z<<<dim3(DIM / 128, (SEQ * B_) / 128), 256, 0, stream>>>(query, W, zhi, zlo);
  // 2) scores -> attn region, pure-load MFMA GEMM
  g2_scores<<<dim3(G2GRID), 256, 0, stream>>>(zhi, zlo, chi, clo, attn);
  // 3) masked softmax in place + bf16 copy (overwrites z region)
  kernel_softmax<<<dim3(SEQ * B_), 256, 0, stream>>>(attn, mask, attnb);
  // 4) comp = attn @ ctx, plain bf16
  g3_comp<<<dim3(DIM / 128, SEQ / 128, B_), 256, 0, stream>>>(attnb, context, comp);
}